// Round 13
// baseline (104.779 us; speedup 1.0000x reference)
//
#include <hip/hip_runtime.h>

#define NROWS 524288
#define THREADS 256
#define NWAVES 4
#define BLOCKS 1024
#define CHUNKS 4
// 1024 blocks * 4 waves * 4 chunks * 32 rows = 524288

using bf16x8 = __bf16 __attribute__((ext_vector_type(8)));
using f32x16 = float __attribute__((ext_vector_type(16)));

union U4 { unsigned u[4]; uint4 q; bf16x8 v; };

// ws frag layout (1KB per frag: 64 lanes x 16B)
// LDS-resident [0..47]:
#define FR_W2T 0    // 36: P2 A = W2^T[b][a] (+bias ks=8)
#define FR_W1E 36   // 4:  L1 A = (w1a,w1a,w1b,w1b,c1h,c1l,0,0)
#define FR_W4T 40   // 5:  dy A = W4^T[0:2][c] (+bias ks=4)
// 45..47 zero pad -> LDS = 48 frags = 49152 B (3 blocks/CU: 144KB <= 160KB)
// L2-streamed [48..65]:
#define FR_W3TS 48  // 18: P3 A = W3^T[c][b] (+bias ks=8), read per chunk via L2

__device__ __forceinline__ f32x16 mfma32(bf16x8 a, bf16x8 b, f32x16 c) {
    return __builtin_amdgcn_mfma_f32_32x32x16_bf16(a, b, c, 0, 0, 0);
}
__device__ __forceinline__ f32x16 z16() {
    f32x16 a = {0,0,0,0,0,0,0,0,0,0,0,0,0,0,0,0};
    return a;
}
__device__ __forceinline__ void silu2(float z, float& h, float& sp) {
    float s = __builtin_amdgcn_rcpf(1.0f + __expf(-z));
    h = z * s;
    sp = fmaf(h, 1.0f - s, s);
}
__device__ __forceinline__ unsigned pkbf(float lo, float hi) {
    unsigned a = (unsigned)__builtin_bit_cast(unsigned short, (__bf16)lo);
    unsigned b = (unsigned)__builtin_bit_cast(unsigned short, (__bf16)hi);
    return a | (b << 16);
}
__device__ __forceinline__ void pl32(unsigned& a, unsigned& b) {
    asm("v_permlane32_swap_b32 %0, %1" : "+v"(a), "+v"(b));
}
__device__ __forceinline__ bf16x8 frg(const unsigned* d) {
    U4 x; x.u[0]=d[0]; x.u[1]=d[1]; x.u[2]=d[2]; x.u[3]=d[3]; return x.v;
}
__device__ __forceinline__ bf16x8 ldf(const char* sm, int off) {
    U4 x; x.q = *(const uint4*)(sm + off); return x.v;
}

// One m-tile's D dwords (8) -> 2 B-frags via permlane32 swap.
__device__ __forceinline__ void xpose1(const unsigned* D8, unsigned (*B)[4]) {
    #pragma unroll
    for (int kb = 0; kb < 2; ++kb)
        #pragma unroll
        for (int jb = 0; jb < 2; ++jb) {
            unsigned a = D8[jb + 4*kb];
            unsigned b = D8[jb + 4*kb + 2];
            pl32(a, b);
            B[kb][jb]   = a;
            B[kb][jb+2] = b;
        }
}

__global__ void prep_kernel(
    const float* __restrict__ W1, const float* __restrict__ b1,
    const float* __restrict__ W2, const float* __restrict__ b2,
    const float* __restrict__ W3, const float* __restrict__ b3,
    const float* __restrict__ W4, const float* __restrict__ b4,
    const float* __restrict__ tp, unsigned* __restrict__ ws)
{
    int t = blockIdx.x * 256 + threadIdx.x;     // 66 frags used
    int fi = t >> 6, lane = t & 63, r31 = lane & 31, g1 = lane >> 5;
    if (fi >= 66) return;
    float val[8];
    #pragma unroll
    for (int i = 0; i < 8; ++i) val[i] = 0.0f;

    if (fi < 36) {                               // W2T: A[b][k=a] = W2[a*128+b]
        int mt = fi/9, ks = fi%9, f = 32*mt + r31;
        if (ks < 8) {
            #pragma unroll
            for (int i = 0; i < 8; ++i) val[i] = W2[(8*g1 + 16*ks + i)*128 + f];
        } else if (g1 == 0) {
            float b = b2[f], bh = (float)(__bf16)b;
            val[0] = bh; val[1] = b - bh;
        }
    } else if (fi < 40) {                        // W1E (layer 1, y-split + c1-split K cols)
        int mt = fi-36, f = 32*mt + r31;
        if (g1 == 0) {
            float wa = W1[f], wb = W1[128 + f];
            float c1 = fmaf(tp[0], W1[256 + f], b1[f]);
            float ch = (float)(__bf16)c1;
            val[0] = wa; val[1] = wa; val[2] = wb; val[3] = wb;
            val[4] = ch; val[5] = c1 - ch;
        }
    } else if (fi < 45) {                        // W4T: A[m][k=c] = W4[c*2+m], m<2
        int ks = fi-40;
        if (ks < 4) {
            if (r31 < 2) {
                #pragma unroll
                for (int i = 0; i < 8; ++i) val[i] = W4[(8*g1 + 16*ks + i)*2 + r31];
            }
        } else if (r31 < 2 && g1 == 0) {
            float b = b4[r31], bh = (float)(__bf16)b;
            val[0] = bh; val[1] = b - bh;
        }
    } else if (fi >= 48) {                       // W3TS: A[c][k=b] = W3[b*64+c]
        int fj = fi-48, mt = fj/9, ks = fj%9, f = 32*mt + r31;
        if (ks < 8) {
            #pragma unroll
            for (int i = 0; i < 8; ++i) val[i] = W3[(8*g1 + 16*ks + i)*64 + f];
        } else if (g1 == 0) {
            float b = b3[f], bh = (float)(__bf16)b;
            val[0] = bh; val[1] = b - bh;
        }
    }

    union { unsigned short s[8]; uint4 q; } o;
    #pragma unroll
    for (int i = 0; i < 8; ++i)
        o.s[i] = __builtin_bit_cast(unsigned short, (__bf16)val[i]);
    ((uint4*)ws)[fi*64 + lane] = o.q;
}

__global__ __launch_bounds__(THREADS, 3)   // 4-wave block, 3 blocks/CU -> 170-reg budget
void cnf_main(
    const float* __restrict__ y, const float* __restrict__ v,
    const unsigned* __restrict__ ws, float* __restrict__ out)
{
    __shared__ __align__(16) char sm[49152];
    const int tid = threadIdx.x, lane = tid & 63, wv = tid >> 6;
    const int r = lane & 31, g1 = lane >> 5;
    const int laneb = lane << 4;

    // stage 48KB frag table -> LDS: 4 waves x 12 x 1KB (frag-linear, conflict-free)
    {
        const char* g = (const char*)ws;
        #pragma unroll
        for (int i = 0; i < 12; ++i) {
            int off = (wv + 4*i) << 10;
            __builtin_amdgcn_global_load_lds(
                (const __attribute__((address_space(1))) unsigned*)(g + off + laneb),
                (__attribute__((address_space(3))) unsigned*)(sm + off), 16, 0, 0);
        }
    }
    __syncthreads();

    bf16x8 onesB = {};
    if (g1 == 0) { onesB[0] = (__bf16)1.0f; onesB[1] = (__bf16)1.0f; }

    const uint4* gW3 = (const uint4*)ws + FR_W3TS*64 + lane;
    const int base = (blockIdx.x * NWAVES + wv) * CHUNKS;
    float2 yc = ((const float2*)y)[base*32 + r];
    float2 vc = ((const float2*)v)[base*32 + r];
    float2 yn = yc, vn = vc;

    #pragma unroll 1
    for (int it = 0; it < CHUNKS; ++it) {
        const int row0 = (base + it) * 32;

        // value B-frag (y hi/lo split) and tangent B-frag (v exact, no bias)
        bf16x8 by = {}, bt = {};
        if (g1 == 0) {
            __bf16 a0 = (__bf16)yc.x; float rr0 = yc.x - (float)a0;
            __bf16 b0 = (__bf16)yc.y; float rr1 = yc.y - (float)b0;
            by[0] = a0; by[1] = (__bf16)rr0; by[2] = b0; by[3] = (__bf16)rr1;
            by[4] = (__bf16)1.0f; by[5] = (__bf16)1.0f;
            bt[0] = (__bf16)vc.x; bt[2] = (__bf16)vc.y;
        }

        unsigned h1B[8][4], t1B[8][4];

        // ---- P1: z1^T = W1e^T @ [y;1]^T ; zt1^T = W1e^T @ [v;0]^T (8 MFMA)
        #pragma unroll
        for (int mt = 0; mt < 4; ++mt) {
            bf16x8 w = ldf(sm, ((FR_W1E+mt)<<10) + laneb);
            f32x16 av = mfma32(w, by, z16());
            f32x16 at = mfma32(w, bt, z16());
            unsigned hd8[8], td8[8];
            #pragma unroll
            for (int j = 0; j < 8; ++j) {
                float h0, s0, h1, s1;
                silu2(av[2*j],   h0, s0);
                silu2(av[2*j+1], h1, s1);
                hd8[j] = pkbf(h0, h1);
                td8[j] = pkbf(s0 * at[2*j], s1 * at[2*j+1]);
            }
            xpose1(hd8, &h1B[2*mt]);
            xpose1(td8, &t1B[2*mt]);
        }

        // issue first two W3T stream frags now: P2's 68 MFMAs hide the L2 latency
        uint4 f0 = gW3[0], f1 = gW3[64];

        // ---- P2: z2^T = W2^T @ h1^T (+b2); zt2^T = W2^T @ t1^T (68 MFMA)
        unsigned h2B[8][4], t2B[8][4];
        #pragma unroll
        for (int mt = 0; mt < 4; ++mt) {
            f32x16 av = z16(), at = z16();
            #pragma unroll
            for (int ks = 0; ks < 9; ++ks) {
                bf16x8 w = ldf(sm, ((FR_W2T + mt*9 + ks)<<10) + laneb);
                av = mfma32(w, ks < 8 ? frg(h1B[ks]) : onesB, av);
                if (ks < 8) at = mfma32(w, frg(t1B[ks]), at);
            }
            unsigned hd8[8], td8[8];
            #pragma unroll
            for (int j = 0; j < 8; ++j) {
                float h0, s0, h1, s1;
                silu2(av[2*j],   h0, s0);
                silu2(av[2*j+1], h1, s1);
                hd8[j] = pkbf(h0, h1);
                td8[j] = pkbf(s0 * at[2*j], s1 * at[2*j+1]);
            }
            xpose1(hd8, &h2B[2*mt]);
            xpose1(td8, &t2B[2*mt]);
        }

        // prefetch next chunk's y/v (consumed next iteration)
        if (it < CHUNKS-1) {
            yn = ((const float2*)y)[row0 + 32 + r];
            vn = ((const float2*)v)[row0 + 32 + r];
        }

        // ---- P3: z3^T = W3^T @ h2^T (+b3); zt3^T = W3^T @ t2^T (34 MFMA)
        //      W3T A-operands streamed from L2, rolling depth-2
        unsigned h3B[4][4], t3B[4][4];
        #pragma unroll
        for (int mt = 0; mt < 2; ++mt) {
            f32x16 av = z16(), at = z16();
            #pragma unroll
            for (int ks = 0; ks < 9; ++ks) {
                const int idx = mt*9 + ks;
                U4 cf; cf.q = f0;
                f0 = f1;
                if (idx + 2 < 18) f1 = gW3[(idx+2)*64];
                av = mfma32(cf.v, ks < 8 ? frg(h2B[ks]) : onesB, av);
                if (ks < 8) at = mfma32(cf.v, frg(t2B[ks]), at);
            }
            unsigned hd8[8], td8[8];
            #pragma unroll
            for (int j = 0; j < 8; ++j) {
                float h0, s0, h1, s1;
                silu2(av[2*j],   h0, s0);
                silu2(av[2*j+1], h1, s1);
                hd8[j] = pkbf(h0, h1);
                td8[j] = pkbf(s0 * at[2*j], s1 * at[2*j+1]);
            }
            xpose1(hd8, &h3B[2*mt]);
            xpose1(td8, &t3B[2*mt]);
        }

        // ---- dy = h3 @ W4 + b4 (5 MFMA); dyt = t3 @ W4 (4 MFMA)
        //      out0 = dy; out1 = -(v . dyt)  [Hutchinson: v^T J v]
        {
            f32x16 a = z16(), b = z16();
            #pragma unroll
            for (int ks = 0; ks < 5; ++ks) {
                bf16x8 w = ldf(sm, ((FR_W4T + ks)<<10) + laneb);
                a = mfma32(w, ks < 4 ? frg(h3B[ks]) : onesB, a);
                if (ks < 4) b = mfma32(w, frg(t3B[ks]), b);
            }
            if (lane < 32) {
                *(float2*)(out + (row0 + r)*2) = make_float2(a[0], a[1]);
                out[2*NROWS + row0 + r] = -(vc.x * b[0] + vc.y * b[1]);
            }
        }

        yc = yn; vc = vn;
    }
}

extern "C" void kernel_launch(void* const* d_in, const int* in_sizes, int n_in,
                              void* d_out, int out_size, void* d_ws, size_t ws_size,
                              hipStream_t stream) {
    const float* y  = (const float*)d_in[0];
    // d_in[1] = logp (unused)
    const float* t  = (const float*)d_in[2];
    const float* v  = (const float*)d_in[3];
    const float* W1 = (const float*)d_in[4];
    const float* b1 = (const float*)d_in[5];
    const float* W2 = (const float*)d_in[6];
    const float* b2 = (const float*)d_in[7];
    const float* W3 = (const float*)d_in[8];
    const float* b3 = (const float*)d_in[9];
    const float* W4 = (const float*)d_in[10];
    const float* b4 = (const float*)d_in[11];

    prep_kernel<<<dim3(17), dim3(256), 0, stream>>>(
        W1, b1, W2, b2, W3, b3, W4, b4, t, (unsigned*)d_ws);
    cnf_main<<<dim3(BLOCKS), dim3(THREADS), 0, stream>>>(
        y, v, (const unsigned*)d_ws, (float*)d_out);
}

// Round 14
// 97.162 us; speedup vs baseline: 1.0784x; 1.0784x over previous
//
#include <hip/hip_runtime.h>

#define NROWS 524288
#define THREADS 512
#define BLOCKS 256
#define CHUNKS 8
// 256 blocks * 8 waves * 8 chunks * 32 rows = 524288

using bf16x8 = __bf16 __attribute__((ext_vector_type(8)));
using f32x16 = float __attribute__((ext_vector_type(16)));

union U4 { unsigned u[4]; uint4 q; bf16x8 v; };

// frag table (1KB per frag: 64 lanes x 16B) — forward-mode only:
#define FR_W2T 0    // 36: P2 A = W2^T[b][a] (+bias ks=8)
#define FR_W3T 36   // 18: P3 A = W3^T[c][b] (+bias ks=8)
#define FR_W1E 54   // 4:  L1 A = (w1a,w1a,w1b,w1b,c1h,c1l,0,0)
#define FR_W4T 58   // 5:  dy A = W4^T[0:2][c] (+bias ks=4); ddy uses ks0..3
// 63 = zero pad -> 64 frags = 65536 B

__device__ __forceinline__ f32x16 mfma32(bf16x8 a, bf16x8 b, f32x16 c) {
    return __builtin_amdgcn_mfma_f32_32x32x16_bf16(a, b, c, 0, 0, 0);
}
__device__ __forceinline__ f32x16 z16() {
    f32x16 a = {0,0,0,0,0,0,0,0,0,0,0,0,0,0,0,0};
    return a;
}
__device__ __forceinline__ void silu2(float z, float& h, float& sp) {
    float s = __builtin_amdgcn_rcpf(1.0f + __expf(-z));
    h = z * s;
    sp = fmaf(h, 1.0f - s, s);
}
__device__ __forceinline__ unsigned pkbf(float lo, float hi) {
    unsigned a = (unsigned)__builtin_bit_cast(unsigned short, (__bf16)lo);
    unsigned b = (unsigned)__builtin_bit_cast(unsigned short, (__bf16)hi);
    return a | (b << 16);
}
__device__ __forceinline__ void pl32(unsigned& a, unsigned& b) {
    asm("v_permlane32_swap_b32 %0, %1" : "+v"(a), "+v"(b));
}
__device__ __forceinline__ bf16x8 frg(const unsigned* d) {
    U4 x; x.u[0]=d[0]; x.u[1]=d[1]; x.u[2]=d[2]; x.u[3]=d[3]; return x.v;
}
__device__ __forceinline__ bf16x8 ldf(const char* sm, int off) {
    U4 x; x.q = *(const uint4*)(sm + off); return x.v;
}

// One m-tile's D dwords (8) -> 2 B-frags via permlane32 swap.
__device__ __forceinline__ void xpose1(const unsigned* D8, unsigned (*B)[4]) {
    #pragma unroll
    for (int kb = 0; kb < 2; ++kb)
        #pragma unroll
        for (int jb = 0; jb < 2; ++jb) {
            unsigned a = D8[jb + 4*kb];
            unsigned b = D8[jb + 4*kb + 2];
            pl32(a, b);
            B[kb][jb]   = a;
            B[kb][jb+2] = b;
        }
}

__global__ void prep_kernel(
    const float* __restrict__ W1, const float* __restrict__ b1,
    const float* __restrict__ W2, const float* __restrict__ b2,
    const float* __restrict__ W3, const float* __restrict__ b3,
    const float* __restrict__ W4, const float* __restrict__ b4,
    const float* __restrict__ tp, unsigned* __restrict__ ws)
{
    int t = blockIdx.x * 256 + threadIdx.x;     // 4096 threads = 64 frags
    int fi = t >> 6, lane = t & 63, r31 = lane & 31, g1 = lane >> 5;
    float val[8];
    #pragma unroll
    for (int i = 0; i < 8; ++i) val[i] = 0.0f;

    if (fi < 36) {                               // W2T: A[b][k=a] = W2[a*128+b]
        int mt = fi/9, ks = fi%9, f = 32*mt + r31;
        if (ks < 8) {
            #pragma unroll
            for (int i = 0; i < 8; ++i) val[i] = W2[(8*g1 + 16*ks + i)*128 + f];
        } else if (g1 == 0) {
            float b = b2[f], bh = (float)(__bf16)b;
            val[0] = bh; val[1] = b - bh;
        }
    } else if (fi < 54) {                        // W3T: A[c][k=b] = W3[b*64+c]
        int fj = fi-36, mt = fj/9, ks = fj%9, f = 32*mt + r31;
        if (ks < 8) {
            #pragma unroll
            for (int i = 0; i < 8; ++i) val[i] = W3[(8*g1 + 16*ks + i)*64 + f];
        } else if (g1 == 0) {
            float b = b3[f], bh = (float)(__bf16)b;
            val[0] = bh; val[1] = b - bh;
        }
    } else if (fi < 58) {                        // W1E (layer 1, y-split + c1-split K cols)
        int mt = fi-54, f = 32*mt + r31;
        if (g1 == 0) {
            float wa = W1[f], wb = W1[128 + f];
            float c1 = fmaf(tp[0], W1[256 + f], b1[f]);
            float ch = (float)(__bf16)c1;
            val[0] = wa; val[1] = wa; val[2] = wb; val[3] = wb;
            val[4] = ch; val[5] = c1 - ch;
        }
    } else if (fi < 63) {                        // W4T: A[m][k=c] = W4[c*2+m], m<2
        int ks = fi-58;
        if (ks < 4) {
            if (r31 < 2) {
                #pragma unroll
                for (int i = 0; i < 8; ++i) val[i] = W4[(8*g1 + 16*ks + i)*2 + r31];
            }
        } else if (r31 < 2 && g1 == 0) {
            float b = b4[r31], bh = (float)(__bf16)b;
            val[0] = bh; val[1] = b - bh;
        }
    }

    union { unsigned short s[8]; uint4 q; } o;
    #pragma unroll
    for (int i = 0; i < 8; ++i)
        o.s[i] = __builtin_bit_cast(unsigned short, (__bf16)val[i]);
    ((uint4*)ws)[fi*64 + lane] = o.q;
}

__global__ __launch_bounds__(THREADS, 2)   // min 2 waves/EU -> 256-reg budget (spill-free)
void cnf_main(
    const float* __restrict__ y, const float* __restrict__ v,
    const unsigned* __restrict__ ws, float* __restrict__ out)
{
    __shared__ __align__(16) char sm[65536];
    const int tid = threadIdx.x, lane = tid & 63, wv = tid >> 6;
    const int r = lane & 31, g1 = lane >> 5;
    const int laneb = lane << 4;

    // stage 64KB frag table -> LDS (frag-linear: conflict-free reads)
    {
        const char* g = (const char*)ws;
        #pragma unroll
        for (int i = 0; i < 8; ++i) {
            int off = i*8192 + wv*1024;
            __builtin_amdgcn_global_load_lds(
                (const __attribute__((address_space(1))) unsigned*)(g + off + laneb),
                (__attribute__((address_space(3))) unsigned*)(sm + off), 16, 0, 0);
        }
    }
    __syncthreads();

    bf16x8 onesB = {};
    if (g1 == 0) { onesB[0] = (__bf16)1.0f; onesB[1] = (__bf16)1.0f; }

    const int base = (blockIdx.x * 8 + wv) * CHUNKS;
    float2 yc = ((const float2*)y)[base*32 + r];
    float2 vc = ((const float2*)v)[base*32 + r];
    float2 yn = yc, vn = vc;

    #pragma unroll 1
    for (int it = 0; it < CHUNKS; ++it) {
        const int row0 = (base + it) * 32;

        // value B-frag (y hi/lo split) and tangent B-frag (v exact, no bias)
        bf16x8 by = {}, bt = {};
        if (g1 == 0) {
            __bf16 a0 = (__bf16)yc.x; float rr0 = yc.x - (float)a0;
            __bf16 b0 = (__bf16)yc.y; float rr1 = yc.y - (float)b0;
            by[0] = a0; by[1] = (__bf16)rr0; by[2] = b0; by[3] = (__bf16)rr1;
            by[4] = (__bf16)1.0f; by[5] = (__bf16)1.0f;
            bt[0] = (__bf16)vc.x; bt[2] = (__bf16)vc.y;
        }

        unsigned h1B[8][4], t1B[8][4];

        // ---- P1: z1^T = W1e^T @ [y;1]^T ; zt1^T = W1e^T @ [v;0]^T (8 MFMA)
        #pragma unroll
        for (int mt = 0; mt < 4; ++mt) {
            bf16x8 w = ldf(sm, ((FR_W1E+mt)<<10) + laneb);
            f32x16 av = mfma32(w, by, z16());
            f32x16 at = mfma32(w, bt, z16());
            unsigned hd8[8], td8[8];
            #pragma unroll
            for (int j = 0; j < 8; ++j) {
                float h0, s0, h1, s1;
                silu2(av[2*j],   h0, s0);
                silu2(av[2*j+1], h1, s1);
                hd8[j] = pkbf(h0, h1);
                td8[j] = pkbf(s0 * at[2*j], s1 * at[2*j+1]);
            }
            xpose1(hd8, &h1B[2*mt]);
            xpose1(td8, &t1B[2*mt]);
        }

        // ---- P2: z2^T = W2^T @ h1^T (+b2); zt2^T = W2^T @ t1^T (68 MFMA)
        unsigned h2B[8][4], t2B[8][4];
        #pragma unroll
        for (int mt = 0; mt < 4; ++mt) {
            f32x16 av = z16(), at = z16();
            #pragma unroll
            for (int ks = 0; ks < 9; ++ks) {
                bf16x8 w = ldf(sm, ((FR_W2T + mt*9 + ks)<<10) + laneb);
                av = mfma32(w, ks < 8 ? frg(h1B[ks]) : onesB, av);
                if (ks < 8) at = mfma32(w, frg(t1B[ks]), at);
            }
            unsigned hd8[8], td8[8];
            #pragma unroll
            for (int j = 0; j < 8; ++j) {
                float h0, s0, h1, s1;
                silu2(av[2*j],   h0, s0);
                silu2(av[2*j+1], h1, s1);
                hd8[j] = pkbf(h0, h1);
                td8[j] = pkbf(s0 * at[2*j], s1 * at[2*j+1]);
            }
            xpose1(hd8, &h2B[2*mt]);
            xpose1(td8, &t2B[2*mt]);
        }

        // prefetch next chunk's y/v (consumed next iteration)
        if (it < CHUNKS-1) {
            yn = ((const float2*)y)[row0 + 32 + r];
            vn = ((const float2*)v)[row0 + 32 + r];
        }

        // ---- P3: z3^T = W3^T @ h2^T (+b3); zt3^T = W3^T @ t2^T (34 MFMA)
        unsigned h3B[4][4], t3B[4][4];
        #pragma unroll
        for (int mt = 0; mt < 2; ++mt) {
            f32x16 av = z16(), at = z16();
            #pragma unroll
            for (int ks = 0; ks < 9; ++ks) {
                bf16x8 w = ldf(sm, ((FR_W3T + mt*9 + ks)<<10) + laneb);
                av = mfma32(w, ks < 8 ? frg(h2B[ks]) : onesB, av);
                if (ks < 8) at = mfma32(w, frg(t2B[ks]), at);
            }
            unsigned hd8[8], td8[8];
            #pragma unroll
            for (int j = 0; j < 8; ++j) {
                float h0, s0, h1, s1;
                silu2(av[2*j],   h0, s0);
                silu2(av[2*j+1], h1, s1);
                hd8[j] = pkbf(h0, h1);
                td8[j] = pkbf(s0 * at[2*j], s1 * at[2*j+1]);
            }
            xpose1(hd8, &h3B[2*mt]);
            xpose1(td8, &t3B[2*mt]);
        }

        // ---- dy = h3 @ W4 + b4 (5 MFMA); dyt = t3 @ W4 (4 MFMA)
        //      out0 = dy; out1 = -(v . dyt)  [Hutchinson: v^T J v]
        {
            f32x16 a = z16(), b = z16();
            #pragma unroll
            for (int ks = 0; ks < 5; ++ks) {
                bf16x8 w = ldf(sm, ((FR_W4T + ks)<<10) + laneb);
                a = mfma32(w, ks < 4 ? frg(h3B[ks]) : onesB, a);
                if (ks < 4) b = mfma32(w, frg(t3B[ks]), b);
            }
            if (lane < 32) {
                *(float2*)(out + (row0 + r)*2) = make_float2(a[0], a[1]);
                out[2*NROWS + row0 + r] = -(vc.x * b[0] + vc.y * b[1]);
            }
        }

        yc = yn; vc = vn;
    }
}

extern "C" void kernel_launch(void* const* d_in, const int* in_sizes, int n_in,
                              void* d_out, int out_size, void* d_ws, size_t ws_size,
                              hipStream_t stream) {
    const float* y  = (const float*)d_in[0];
    // d_in[1] = logp (unused)
    const float* t  = (const float*)d_in[2];
    const float* v  = (const float*)d_in[3];
    const float* W1 = (const float*)d_in[4];
    const float* b1 = (const float*)d_in[5];
    const float* W2 = (const float*)d_in[6];
    const float* b2 = (const float*)d_in[7];
    const float* W3 = (const float*)d_in[8];
    const float* b3 = (const float*)d_in[9];
    const float* W4 = (const float*)d_in[10];
    const float* b4 = (const float*)d_in[11];

    prep_kernel<<<dim3(16), dim3(256), 0, stream>>>(
        W1, b1, W2, b2, W3, b3, W4, b4, t, (unsigned*)d_ws);
    cnf_main<<<dim3(BLOCKS), dim3(THREADS), 0, stream>>>(
        y, v, (const unsigned*)d_ws, (float*)d_out);
}

// Round 15
// 94.016 us; speedup vs baseline: 1.1145x; 1.0335x over previous
//
#include <hip/hip_runtime.h>

#define NROWS 524288
#define THREADS 512
#define BLOCKS 512
#define CHUNKS 4
// 512 blocks * 8 waves * 4 chunks * 32 rows = 524288

using bf16x8 = __bf16 __attribute__((ext_vector_type(8)));
using f32x16 = float __attribute__((ext_vector_type(16)));

union U4 { unsigned u[4]; uint4 q; bf16x8 v; };

// frag table (1KB per frag: 64 lanes x 16B) — forward-mode only:
#define FR_W2T 0    // 36: P2 A = W2^T[b][a] (+bias ks=8)
#define FR_W3T 36   // 18: P3 A = W3^T[c][b] (+bias ks=8)
#define FR_W1E 54   // 4:  L1 A = (w1a,w1a,w1b,w1b,c1h,c1l,0,0)
#define FR_W4T 58   // 5:  dy A = W4^T[0:2][c] (+bias ks=4); ddy uses ks0..3
// 63 = zero pad -> 64 frags = 65536 B

__device__ __forceinline__ f32x16 mfma32(bf16x8 a, bf16x8 b, f32x16 c) {
    return __builtin_amdgcn_mfma_f32_32x32x16_bf16(a, b, c, 0, 0, 0);
}
__device__ __forceinline__ f32x16 z16() {
    f32x16 a = {0,0,0,0,0,0,0,0,0,0,0,0,0,0,0,0};
    return a;
}
__device__ __forceinline__ void silu2(float z, float& h, float& sp) {
    float s = __builtin_amdgcn_rcpf(1.0f + __expf(-z));
    h = z * s;
    sp = fmaf(h, 1.0f - s, s);
}
__device__ __forceinline__ unsigned pkbf(float lo, float hi) {
    unsigned a = (unsigned)__builtin_bit_cast(unsigned short, (__bf16)lo);
    unsigned b = (unsigned)__builtin_bit_cast(unsigned short, (__bf16)hi);
    return a | (b << 16);
}
__device__ __forceinline__ void pl32(unsigned& a, unsigned& b) {
    asm("v_permlane32_swap_b32 %0, %1" : "+v"(a), "+v"(b));
}
__device__ __forceinline__ bf16x8 frg(const unsigned* d) {
    U4 x; x.u[0]=d[0]; x.u[1]=d[1]; x.u[2]=d[2]; x.u[3]=d[3]; return x.v;
}
__device__ __forceinline__ bf16x8 ldf(const char* sm, int off) {
    U4 x; x.q = *(const uint4*)(sm + off); return x.v;
}

// One m-tile's D dwords (8) -> 2 B-frags via permlane32 swap.
__device__ __forceinline__ void xpose1(const unsigned* D8, unsigned (*B)[4]) {
    #pragma unroll
    for (int kb = 0; kb < 2; ++kb)
        #pragma unroll
        for (int jb = 0; jb < 2; ++jb) {
            unsigned a = D8[jb + 4*kb];
            unsigned b = D8[jb + 4*kb + 2];
            pl32(a, b);
            B[kb][jb]   = a;
            B[kb][jb+2] = b;
        }
}

__global__ void prep_kernel(
    const float* __restrict__ W1, const float* __restrict__ b1,
    const float* __restrict__ W2, const float* __restrict__ b2,
    const float* __restrict__ W3, const float* __restrict__ b3,
    const float* __restrict__ W4, const float* __restrict__ b4,
    const float* __restrict__ tp, unsigned* __restrict__ ws)
{
    int t = blockIdx.x * 256 + threadIdx.x;     // 4096 threads = 64 frags
    int fi = t >> 6, lane = t & 63, r31 = lane & 31, g1 = lane >> 5;
    float val[8];
    #pragma unroll
    for (int i = 0; i < 8; ++i) val[i] = 0.0f;

    if (fi < 36) {                               // W2T: A[b][k=a] = W2[a*128+b]
        int mt = fi/9, ks = fi%9, f = 32*mt + r31;
        if (ks < 8) {
            #pragma unroll
            for (int i = 0; i < 8; ++i) val[i] = W2[(8*g1 + 16*ks + i)*128 + f];
        } else if (g1 == 0) {
            float b = b2[f], bh = (float)(__bf16)b;
            val[0] = bh; val[1] = b - bh;
        }
    } else if (fi < 54) {                        // W3T: A[c][k=b] = W3[b*64+c]
        int fj = fi-36, mt = fj/9, ks = fj%9, f = 32*mt + r31;
        if (ks < 8) {
            #pragma unroll
            for (int i = 0; i < 8; ++i) val[i] = W3[(8*g1 + 16*ks + i)*64 + f];
        } else if (g1 == 0) {
            float b = b3[f], bh = (float)(__bf16)b;
            val[0] = bh; val[1] = b - bh;
        }
    } else if (fi < 58) {                        // W1E (layer 1, y-split + c1-split K cols)
        int mt = fi-54, f = 32*mt + r31;
        if (g1 == 0) {
            float wa = W1[f], wb = W1[128 + f];
            float c1 = fmaf(tp[0], W1[256 + f], b1[f]);
            float ch = (float)(__bf16)c1;
            val[0] = wa; val[1] = wa; val[2] = wb; val[3] = wb;
            val[4] = ch; val[5] = c1 - ch;
        }
    } else if (fi < 63) {                        // W4T: A[m][k=c] = W4[c*2+m], m<2
        int ks = fi-58;
        if (ks < 4) {
            if (r31 < 2) {
                #pragma unroll
                for (int i = 0; i < 8; ++i) val[i] = W4[(8*g1 + 16*ks + i)*2 + r31];
            }
        } else if (r31 < 2 && g1 == 0) {
            float b = b4[r31], bh = (float)(__bf16)b;
            val[0] = bh; val[1] = b - bh;
        }
    }

    union { unsigned short s[8]; uint4 q; } o;
    #pragma unroll
    for (int i = 0; i < 8; ++i)
        o.s[i] = __builtin_bit_cast(unsigned short, (__bf16)val[i]);
    ((uint4*)ws)[fi*64 + lane] = o.q;
}

__global__ __launch_bounds__(THREADS, 2)   // min 2 waves/EU -> 256-reg budget (spill-free)
void cnf_main(
    const float* __restrict__ y, const float* __restrict__ v,
    const unsigned* __restrict__ ws, float* __restrict__ out)
{
    __shared__ __align__(16) char sm[65536];
    const int tid = threadIdx.x, lane = tid & 63, wv = tid >> 6;
    const int r = lane & 31, g1 = lane >> 5;
    const int laneb = lane << 4;

    // stage 64KB frag table -> LDS (frag-linear: conflict-free reads)
    {
        const char* g = (const char*)ws;
        #pragma unroll
        for (int i = 0; i < 8; ++i) {
            int off = i*8192 + wv*1024;
            __builtin_amdgcn_global_load_lds(
                (const __attribute__((address_space(1))) unsigned*)(g + off + laneb),
                (__attribute__((address_space(3))) unsigned*)(sm + off), 16, 0, 0);
        }
    }
    __syncthreads();

    // phase-stagger: desync the second wave on each SIMD (round-robin wv->SIMD
    // assumed: partners are wv and wv+4) by ~7K cycles so MFMA-phase of one
    // overlaps VALU-phase of the other for the whole barrier-free chunk loop.
    if (wv >= 4) {
        #pragma unroll
        for (int i = 0; i < 16; ++i) __builtin_amdgcn_s_sleep(7);
    }

    bf16x8 onesB = {};
    if (g1 == 0) { onesB[0] = (__bf16)1.0f; onesB[1] = (__bf16)1.0f; }

    const int base = (blockIdx.x * 8 + wv) * CHUNKS;
    float2 yc = ((const float2*)y)[base*32 + r];
    float2 vc = ((const float2*)v)[base*32 + r];
    float2 yn = yc, vn = vc;

    #pragma unroll 1
    for (int it = 0; it < CHUNKS; ++it) {
        const int row0 = (base + it) * 32;

        // value B-frag (y hi/lo split) and tangent B-frag (v exact, no bias)
        bf16x8 by = {}, bt = {};
        if (g1 == 0) {
            __bf16 a0 = (__bf16)yc.x; float rr0 = yc.x - (float)a0;
            __bf16 b0 = (__bf16)yc.y; float rr1 = yc.y - (float)b0;
            by[0] = a0; by[1] = (__bf16)rr0; by[2] = b0; by[3] = (__bf16)rr1;
            by[4] = (__bf16)1.0f; by[5] = (__bf16)1.0f;
            bt[0] = (__bf16)vc.x; bt[2] = (__bf16)vc.y;
        }

        unsigned h1B[8][4], t1B[8][4];

        // ---- P1: z1^T = W1e^T @ [y;1]^T ; zt1^T = W1e^T @ [v;0]^T (8 MFMA)
        #pragma unroll
        for (int mt = 0; mt < 4; ++mt) {
            bf16x8 w = ldf(sm, ((FR_W1E+mt)<<10) + laneb);
            f32x16 av = mfma32(w, by, z16());
            f32x16 at = mfma32(w, bt, z16());
            unsigned hd8[8], td8[8];
            #pragma unroll
            for (int j = 0; j < 8; ++j) {
                float h0, s0, h1, s1;
                silu2(av[2*j],   h0, s0);
                silu2(av[2*j+1], h1, s1);
                hd8[j] = pkbf(h0, h1);
                td8[j] = pkbf(s0 * at[2*j], s1 * at[2*j+1]);
            }
            xpose1(hd8, &h1B[2*mt]);
            xpose1(td8, &t1B[2*mt]);
        }

        // ---- P2: z2^T = W2^T @ h1^T (+b2); zt2^T = W2^T @ t1^T (68 MFMA)
        unsigned h2B[8][4], t2B[8][4];
        #pragma unroll
        for (int mt = 0; mt < 4; ++mt) {
            f32x16 av = z16(), at = z16();
            #pragma unroll
            for (int ks = 0; ks < 9; ++ks) {
                bf16x8 w = ldf(sm, ((FR_W2T + mt*9 + ks)<<10) + laneb);
                av = mfma32(w, ks < 8 ? frg(h1B[ks]) : onesB, av);
                if (ks < 8) at = mfma32(w, frg(t1B[ks]), at);
            }
            unsigned hd8[8], td8[8];
            #pragma unroll
            for (int j = 0; j < 8; ++j) {
                float h0, s0, h1, s1;
                silu2(av[2*j],   h0, s0);
                silu2(av[2*j+1], h1, s1);
                hd8[j] = pkbf(h0, h1);
                td8[j] = pkbf(s0 * at[2*j], s1 * at[2*j+1]);
            }
            xpose1(hd8, &h2B[2*mt]);
            xpose1(td8, &t2B[2*mt]);
        }

        // prefetch next chunk's y/v (consumed next iteration)
        if (it < CHUNKS-1) {
            yn = ((const float2*)y)[row0 + 32 + r];
            vn = ((const float2*)v)[row0 + 32 + r];
        }

        // ---- P3: z3^T = W3^T @ h2^T (+b3); zt3^T = W3^T @ t2^T (34 MFMA)
        unsigned h3B[4][4], t3B[4][4];
        #pragma unroll
        for (int mt = 0; mt < 2; ++mt) {
            f32x16 av = z16(), at = z16();
            #pragma unroll
            for (int ks = 0; ks < 9; ++ks) {
                bf16x8 w = ldf(sm, ((FR_W3T + mt*9 + ks)<<10) + laneb);
                av = mfma32(w, ks < 8 ? frg(h2B[ks]) : onesB, av);
                if (ks < 8) at = mfma32(w, frg(t2B[ks]), at);
            }
            unsigned hd8[8], td8[8];
            #pragma unroll
            for (int j = 0; j < 8; ++j) {
                float h0, s0, h1, s1;
                silu2(av[2*j],   h0, s0);
                silu2(av[2*j+1], h1, s1);
                hd8[j] = pkbf(h0, h1);
                td8[j] = pkbf(s0 * at[2*j], s1 * at[2*j+1]);
            }
            xpose1(hd8, &h3B[2*mt]);
            xpose1(td8, &t3B[2*mt]);
        }

        // ---- dy = h3 @ W4 + b4 (5 MFMA); dyt = t3 @ W4 (4 MFMA)
        //      out0 = dy; out1 = -(v . dyt)  [Hutchinson: v^T J v]
        {
            f32x16 a = z16(), b = z16();
            #pragma unroll
            for (int ks = 0; ks < 5; ++ks) {
                bf16x8 w = ldf(sm, ((FR_W4T + ks)<<10) + laneb);
                a = mfma32(w, ks < 4 ? frg(h3B[ks]) : onesB, a);
                if (ks < 4) b = mfma32(w, frg(t3B[ks]), b);
            }
            if (lane < 32) {
                *(float2*)(out + (row0 + r)*2) = make_float2(a[0], a[1]);
                out[2*NROWS + row0 + r] = -(vc.x * b[0] + vc.y * b[1]);
            }
        }

        yc = yn; vc = vn;
    }
}

extern "C" void kernel_launch(void* const* d_in, const int* in_sizes, int n_in,
                              void* d_out, int out_size, void* d_ws, size_t ws_size,
                              hipStream_t stream) {
    const float* y  = (const float*)d_in[0];
    // d_in[1] = logp (unused)
    const float* t  = (const float*)d_in[2];
    const float* v  = (const float*)d_in[3];
    const float* W1 = (const float*)d_in[4];
    const float* b1 = (const float*)d_in[5];
    const float* W2 = (const float*)d_in[6];
    const float* b2 = (const float*)d_in[7];
    const float* W3 = (const float*)d_in[8];
    const float* b3 = (const float*)d_in[9];
    const float* W4 = (const float*)d_in[10];
    const float* b4 = (const float*)d_in[11];

    prep_kernel<<<dim3(16), dim3(256), 0, stream>>>(
        W1, b1, W2, b2, W3, b3, W4, b4, t, (unsigned*)d_ws);
    cnf_main<<<dim3(BLOCKS), dim3(THREADS), 0, stream>>>(
        y, v, (const unsigned*)d_ws, (float*)d_out);
}

// Round 17
// 92.781 us; speedup vs baseline: 1.1293x; 1.0133x over previous
//
#include <hip/hip_runtime.h>

#define NROWS 524288
#define THREADS 512
#define BLOCKS 512
#define CHUNKS 4
// 512 blocks * 8 waves * 4 chunks * 32 rows = 524288

using bf16x8 = __bf16 __attribute__((ext_vector_type(8)));
using f32x16 = float __attribute__((ext_vector_type(16)));

union U4 { unsigned u[4]; uint4 q; bf16x8 v; };

// frag table (1KB per frag: 64 lanes x 16B) — forward-mode only:
#define FR_W2T 0    // 36: P2 A = W2^T[b][a] (+bias ks=8)
#define FR_W3T 36   // 18: P3 A = W3^T[c][b] (+bias ks=8)
#define FR_W1E 54   // 4:  L1 A = (w1a,w1a,w1b,w1b,c1h,c1l,0,0)
#define FR_W4T 58   // 5:  dy A = W4^T[0:2][c] (+bias ks=4); ddy uses ks0..3
// 63 = zero pad -> 64 frags = 65536 B

__device__ __forceinline__ f32x16 mfma32(bf16x8 a, bf16x8 b, f32x16 c) {
    return __builtin_amdgcn_mfma_f32_32x32x16_bf16(a, b, c, 0, 0, 0);
}
__device__ __forceinline__ f32x16 z16() {
    f32x16 a = {0,0,0,0,0,0,0,0,0,0,0,0,0,0,0,0};
    return a;
}
__device__ __forceinline__ void silu2(float z, float& h, float& sp) {
    float s = __builtin_amdgcn_rcpf(1.0f + __expf(-z));
    h = z * s;
    sp = fmaf(h, 1.0f - s, s);
}
// pack f32 pair -> bf16x2 dword; scalar casts + shift/or.
// NOTE (R8/R9/R16 measured): bf16x2 vector-build and f32x2 pk-math variants
// BOTH break accuracy (2^-5-class errors) — this scalar RNE path is required.
__device__ __forceinline__ unsigned pkbf(float lo, float hi) {
    unsigned a = (unsigned)__builtin_bit_cast(unsigned short, (__bf16)lo);
    unsigned b = (unsigned)__builtin_bit_cast(unsigned short, (__bf16)hi);
    return a | (b << 16);
}
__device__ __forceinline__ void pl32(unsigned& a, unsigned& b) {
    asm("v_permlane32_swap_b32 %0, %1" : "+v"(a), "+v"(b));
}
__device__ __forceinline__ bf16x8 frg(const unsigned* d) {
    U4 x; x.u[0]=d[0]; x.u[1]=d[1]; x.u[2]=d[2]; x.u[3]=d[3]; return x.v;
}
__device__ __forceinline__ bf16x8 ldf(const char* sm, int off) {
    U4 x; x.q = *(const uint4*)(sm + off); return x.v;
}

// One m-tile's D dwords (8) -> 2 B-frags via permlane32 swap.
__device__ __forceinline__ void xpose1(const unsigned* D8, unsigned (*B)[4]) {
    #pragma unroll
    for (int kb = 0; kb < 2; ++kb)
        #pragma unroll
        for (int jb = 0; jb < 2; ++jb) {
            unsigned a = D8[jb + 4*kb];
            unsigned b = D8[jb + 4*kb + 2];
            pl32(a, b);
            B[kb][jb]   = a;
            B[kb][jb+2] = b;
        }
}

__global__ void prep_kernel(
    const float* __restrict__ W1, const float* __restrict__ b1,
    const float* __restrict__ W2, const float* __restrict__ b2,
    const float* __restrict__ W3, const float* __restrict__ b3,
    const float* __restrict__ W4, const float* __restrict__ b4,
    const float* __restrict__ tp, unsigned* __restrict__ ws)
{
    int t = blockIdx.x * 256 + threadIdx.x;     // 4096 threads = 64 frags
    int fi = t >> 6, lane = t & 63, r31 = lane & 31, g1 = lane >> 5;
    float val[8];
    #pragma unroll
    for (int i = 0; i < 8; ++i) val[i] = 0.0f;

    if (fi < 36) {                               // W2T: A[b][k=a] = W2[a*128+b]
        int mt = fi/9, ks = fi%9, f = 32*mt + r31;
        if (ks < 8) {
            #pragma unroll
            for (int i = 0; i < 8; ++i) val[i] = W2[(8*g1 + 16*ks + i)*128 + f];
        } else if (g1 == 0) {
            float b = b2[f], bh = (float)(__bf16)b;
            val[0] = bh; val[1] = b - bh;
        }
    } else if (fi < 54) {                        // W3T: A[c][k=b] = W3[b*64+c]
        int fj = fi-36, mt = fj/9, ks = fj%9, f = 32*mt + r31;
        if (ks < 8) {
            #pragma unroll
            for (int i = 0; i < 8; ++i) val[i] = W3[(8*g1 + 16*ks + i)*64 + f];
        } else if (g1 == 0) {
            float b = b3[f], bh = (float)(__bf16)b;
            val[0] = bh; val[1] = b - bh;
        }
    } else if (fi < 58) {                        // W1E (layer 1, y-split + c1-split K cols)
        int mt = fi-54, f = 32*mt + r31;
        if (g1 == 0) {
            float wa = W1[f], wb = W1[128 + f];
            float c1 = fmaf(tp[0], W1[256 + f], b1[f]);
            float ch = (float)(__bf16)c1;
            val[0] = wa; val[1] = wa; val[2] = wb; val[3] = wb;
            val[4] = ch; val[5] = c1 - ch;
        }
    } else if (fi < 63) {                        // W4T: A[m][k=c] = W4[c*2+m], m<2
        int ks = fi-58;
        if (ks < 4) {
            if (r31 < 2) {
                #pragma unroll
                for (int i = 0; i < 8; ++i) val[i] = W4[(8*g1 + 16*ks + i)*2 + r31];
            }
        } else if (r31 < 2 && g1 == 0) {
            float b = b4[r31], bh = (float)(__bf16)b;
            val[0] = bh; val[1] = b - bh;
        }
    }

    union { unsigned short s[8]; uint4 q; } o;
    #pragma unroll
    for (int i = 0; i < 8; ++i)
        o.s[i] = __builtin_bit_cast(unsigned short, (__bf16)val[i]);
    ((uint4*)ws)[fi*64 + lane] = o.q;
}

__global__ __launch_bounds__(THREADS, 2)   // min 2 waves/EU -> 256-reg budget (spill-free)
void cnf_main(
    const float* __restrict__ y, const float* __restrict__ v,
    const unsigned* __restrict__ ws, float* __restrict__ out)
{
    __shared__ __align__(16) char sm[65536];
    const int tid = threadIdx.x, lane = tid & 63, wv = tid >> 6;
    const int r = lane & 31, g1 = lane >> 5;
    const int laneb = lane << 4;

    // stage 64KB frag table -> LDS (frag-linear: conflict-free reads)
    {
        const char* g = (const char*)ws;
        #pragma unroll
        for (int i = 0; i < 8; ++i) {
            int off = i*8192 + wv*1024;
            __builtin_amdgcn_global_load_lds(
                (const __attribute__((address_space(1))) unsigned*)(g + off + laneb),
                (__attribute__((address_space(3))) unsigned*)(sm + off), 16, 0, 0);
        }
    }
    __syncthreads();

    bf16x8 onesB = {};
    if (g1 == 0) { onesB[0] = (__bf16)1.0f; onesB[1] = (__bf16)1.0f; }

    const int base = (blockIdx.x * 8 + wv) * CHUNKS;
    float2 yc = ((const float2*)y)[base*32 + r];
    float2 vc = ((const float2*)v)[base*32 + r];
    float2 yn = yc, vn = vc;

    #pragma unroll 1
    for (int it = 0; it < CHUNKS; ++it) {
        const int row0 = (base + it) * 32;

        // value B-frag (y hi/lo split) and tangent B-frag (v exact, no bias)
        bf16x8 by = {}, bt = {};
        if (g1 == 0) {
            __bf16 a0 = (__bf16)yc.x; float rr0 = yc.x - (float)a0;
            __bf16 b0 = (__bf16)yc.y; float rr1 = yc.y - (float)b0;
            by[0] = a0; by[1] = (__bf16)rr0; by[2] = b0; by[3] = (__bf16)rr1;
            by[4] = (__bf16)1.0f; by[5] = (__bf16)1.0f;
            bt[0] = (__bf16)vc.x; bt[2] = (__bf16)vc.y;
        }

        unsigned h1B[8][4], t1B[8][4];

        // ---- P1: z1^T = W1e^T @ [y;1]^T ; zt1^T = W1e^T @ [v;0]^T (8 MFMA)
        #pragma unroll
        for (int mt = 0; mt < 4; ++mt) {
            bf16x8 w = ldf(sm, ((FR_W1E+mt)<<10) + laneb);
            f32x16 av = mfma32(w, by, z16());
            f32x16 at = mfma32(w, bt, z16());
            unsigned hd8[8], td8[8];
            #pragma unroll
            for (int j = 0; j < 8; ++j) {
                float h0, s0, h1, s1;
                silu2(av[2*j],   h0, s0);
                silu2(av[2*j+1], h1, s1);
                hd8[j] = pkbf(h0, h1);
                td8[j] = pkbf(s0 * at[2*j], s1 * at[2*j+1]);
            }
            xpose1(hd8, &h1B[2*mt]);
            xpose1(td8, &t1B[2*mt]);
        }

        // ---- P2: z2^T = W2^T @ h1^T (+b2); zt2^T = W2^T @ t1^T (68 MFMA)
        unsigned h2B[8][4], t2B[8][4];
        #pragma unroll
        for (int mt = 0; mt < 4; ++mt) {
            f32x16 av = z16(), at = z16();
            #pragma unroll
            for (int ks = 0; ks < 9; ++ks) {
                bf16x8 w = ldf(sm, ((FR_W2T + mt*9 + ks)<<10) + laneb);
                av = mfma32(w, ks < 8 ? frg(h1B[ks]) : onesB, av);
                if (ks < 8) at = mfma32(w, frg(t1B[ks]), at);
            }
            unsigned hd8[8], td8[8];
            #pragma unroll
            for (int j = 0; j < 8; ++j) {
                float h0, s0, h1, s1;
                silu2(av[2*j],   h0, s0);
                silu2(av[2*j+1], h1, s1);
                hd8[j] = pkbf(h0, h1);
                td8[j] = pkbf(s0 * at[2*j], s1 * at[2*j+1]);
            }
            xpose1(hd8, &h2B[2*mt]);
            xpose1(td8, &t2B[2*mt]);
        }

        // prefetch next chunk's y/v (consumed next iteration)
        if (it < CHUNKS-1) {
            yn = ((const float2*)y)[row0 + 32 + r];
            vn = ((const float2*)v)[row0 + 32 + r];
        }

        // ---- P3: z3^T = W3^T @ h2^T (+b3); zt3^T = W3^T @ t2^T (34 MFMA)
        unsigned h3B[4][4], t3B[4][4];
        #pragma unroll
        for (int mt = 0; mt < 2; ++mt) {
            f32x16 av = z16(), at = z16();
            #pragma unroll
            for (int ks = 0; ks < 9; ++ks) {
                bf16x8 w = ldf(sm, ((FR_W3T + mt*9 + ks)<<10) + laneb);
                av = mfma32(w, ks < 8 ? frg(h2B[ks]) : onesB, av);
                if (ks < 8) at = mfma32(w, frg(t2B[ks]), at);
            }
            unsigned hd8[8], td8[8];
            #pragma unroll
            for (int j = 0; j < 8; ++j) {
                float h0, s0, h1, s1;
                silu2(av[2*j],   h0, s0);
                silu2(av[2*j+1], h1, s1);
                hd8[j] = pkbf(h0, h1);
                td8[j] = pkbf(s0 * at[2*j], s1 * at[2*j+1]);
            }
            xpose1(hd8, &h3B[2*mt]);
            xpose1(td8, &t3B[2*mt]);
        }

        // ---- dy = h3 @ W4 + b4 (5 MFMA); dyt = t3 @ W4 (4 MFMA)
        //      out0 = dy; out1 = -(v . dyt)  [Hutchinson: v^T J v]
        {
            f32x16 a = z16(), b = z16();
            #pragma unroll
            for (int ks = 0; ks < 5; ++ks) {
                bf16x8 w = ldf(sm, ((FR_W4T + ks)<<10) + laneb);
                a = mfma32(w, ks < 4 ? frg(h3B[ks]) : onesB, a);
                if (ks < 4) b = mfma32(w, frg(t3B[ks]), b);
            }
            if (lane < 32) {
                *(float2*)(out + (row0 + r)*2) = make_float2(a[0], a[1]);
                out[2*NROWS + row0 + r] = -(vc.x * b[0] + vc.y * b[1]);
            }
        }

        yc = yn; vc = vn;
    }
}

extern "C" void kernel_launch(void* const* d_in, const int* in_sizes, int n_in,
                              void* d_out, int out_size, void* d_ws, size_t ws_size,
                              hipStream_t stream) {
    const float* y  = (const float*)d_in[0];
    // d_in[1] = logp (unused)
    const float* t  = (const float*)d_in[2];
    const float* v  = (const float*)d_in[3];
    const float* W1 = (const float*)d_in[4];
    const float* b1 = (const float*)d_in[5];
    const float* W2 = (const float*)d_in[6];
    const float* b2 = (const float*)d_in[7];
    const float* W3 = (const float*)d_in[8];
    const float* b3 = (const float*)d_in[9];
    const float* W4 = (const float*)d_in[10];
    const float* b4 = (const float*)d_in[11];

    prep_kernel<<<dim3(16), dim3(256), 0, stream>>>(
        W1, b1, W2, b2, W3, b3, W4, b4, t, (unsigned*)d_ws);
    cnf_main<<<dim3(BLOCKS), dim3(THREADS), 0, stream>>>(
        y, v, (const unsigned*)d_ws, (float*)d_out);
}